// Round 1
// baseline (1963.298 us; speedup 1.0000x reference)
//
#include <hip/hip_runtime.h>
#include <cstdint>
#include <climits>
#include <math.h>

#define NN 50000
#define EE 1600000
#define ET (EE + NN)   // real edges + one self-loop per node
#define GG 512
#define NEG_SLOPE 0.2f
#define NB 196          // ceil(NN/256) scan blocks

typedef _Float16 half2v __attribute__((ext_vector_type(2)));

__device__ __forceinline__ uint32_t packh2(float a, float b) {
    union { half2v h; uint32_t u; } c;
    c.h = half2v{(_Float16)a, (_Float16)b};
    return c.u;
}
__device__ __forceinline__ float fdot2u(uint32_t a, uint32_t b, float c) {
    union { uint32_t u; half2v h; } ua, ub;
    ua.u = a; ub.u = b;
    return __builtin_amdgcn_fdot2(ua.h, ub.h, c, false);
}
__device__ __forceinline__ float rlanef(float v, int l) {
    return __int_as_float(__builtin_amdgcn_readlane(__float_as_int(v), l));
}

// ---------- degree histogram ----------
__global__ void k_hist(const int* __restrict__ dst, int* __restrict__ hist) {
    int e = blockIdx.x * blockDim.x + threadIdx.x;
    if (e < EE) atomicAdd(&hist[dst[e]], 1);
}

// ---------- CSR build: scan of hist then scatter (real edges only) ----------
__global__ void k_scan_a(const int* __restrict__ hist, int* __restrict__ bsum) {
    __shared__ int tmp[256];
    int i = blockIdx.x * 256 + threadIdx.x;
    tmp[threadIdx.x] = (i < NN) ? hist[i] : 0;
    __syncthreads();
    for (int d = 128; d; d >>= 1) {
        if (threadIdx.x < d) tmp[threadIdx.x] += tmp[threadIdx.x + d];
        __syncthreads();
    }
    if (threadIdx.x == 0) bsum[blockIdx.x] = tmp[0];
}

__global__ void k_scan_b(int* __restrict__ bsum, int* __restrict__ rowptr) {
    int acc = 0;
    for (int b = 0; b < NB; b++) { int v = bsum[b]; bsum[b] = acc; acc += v; }
    rowptr[NN] = acc;  // == EE
}

__global__ void k_scan_c(const int* __restrict__ hist, const int* __restrict__ bsum,
                         int* __restrict__ rowptr) {
    __shared__ int tmp[256];
    int i = blockIdx.x * 256 + threadIdx.x;
    int v = (i < NN) ? hist[i] : 0;
    tmp[threadIdx.x] = v;
    __syncthreads();
    for (int d = 1; d < 256; d <<= 1) {
        int t = (threadIdx.x >= d) ? tmp[threadIdx.x - d] : 0;
        __syncthreads();
        tmp[threadIdx.x] += t;
        __syncthreads();
    }
    if (i < NN) rowptr[i] = tmp[threadIdx.x] - v + bsum[blockIdx.x];
}

__global__ void k_cursor_init(const int* __restrict__ rowptr, int* __restrict__ cursor) {
    int i = blockIdx.x * blockDim.x + threadIdx.x;
    if (i < NN) cursor[i] = rowptr[i];
}

__global__ void k_scatter(const int* __restrict__ dst, int* __restrict__ cursor,
                          int* __restrict__ csr_eid, int* __restrict__ csr_dst) {
    int e = blockIdx.x * blockDim.x + threadIdx.x;
    if (e < EE) {
        int d = dst[e];
        int p = atomicAdd(&cursor[d], 1);
        csr_eid[p] = e;
        csr_dst[p] = d;
    }
}

// ---------- csr_src[pos] = srcv[csr_eid[pos]] ----------
__global__ void k_csr_src(const int* __restrict__ csr_eid, const int* __restrict__ srcv,
                          int* __restrict__ csr_src) {
    int p = blockIdx.x * blockDim.x + threadIdx.x;
    if (p < EE) csr_src[p] = srcv[csr_eid[p]];
}

// ---------- pack ea rows to fp16 SoA planes in CSR order ----------
__global__ void k_pack2(const int* __restrict__ csr_eid, const float* __restrict__ ea,
                        uint32_t* __restrict__ eah2) {
    int pos = blockIdx.x * blockDim.x + threadIdx.x;
    if (pos >= EE) return;
    int e = csr_eid[pos];
    const float* r = ea + (size_t)e * 18;
#pragma unroll
    for (int kk = 0; kk < 9; kk++) {
        float2 q = *(const float2*)(r + 2 * kk);
        eah2[(size_t)kk * ET + pos] = packh2(q.x, q.y);
    }
}

// ---------- self-loop edge attr = mean of incoming ea (fill_value='mean') ----------
__global__ void __launch_bounds__(256)
k_loop(const int* __restrict__ rowptr, uint32_t* __restrict__ eah2,
       int* __restrict__ csr_src, int* __restrict__ csr_dst) {
    const int lane = threadIdx.x & 63;
    int wid = blockIdx.x * (blockDim.x >> 6) + (threadIdx.x >> 6);
    int nw = gridDim.x * (blockDim.x >> 6);
    const int kk = lane & 15;
    const int t4 = lane >> 4;
    const bool a9 = kk < 9;

    for (int i = wid; i < NN; i += nw) {
        int beg = __builtin_amdgcn_readfirstlane(rowptr[i]);
        int end = __builtin_amdgcn_readfirstlane(rowptr[i + 1]);
        float ax = 0.f, ay = 0.f;
        if (a9) {
            const uint32_t* p = eah2 + (size_t)kk * ET;
#pragma unroll 4
            for (int e = beg + t4; e < end; e += 4) {
                union { uint32_t u; half2v h; } q;
                q.u = p[e];
                ax += (float)q.h.x;
                ay += (float)q.h.y;
            }
        }
        ax += __shfl_xor(ax, 16, 64); ax += __shfl_xor(ax, 32, 64);
        ay += __shfl_xor(ay, 16, 64); ay += __shfl_xor(ay, 32, 64);
        if (a9 && t4 == 0) {
            int deg = end - beg;
            float rd = (deg > 0) ? 1.0f / (float)deg : 0.0f;
            eah2[(size_t)kk * ET + EE + i] = packh2(ax * rd, ay * rd);
        }
        if (lane == 0) { csr_src[EE + i] = i; csr_dst[EE + i] = i; }
    }
}

// ---------- pack WeT: group g = 4 features; per feature: 9 fp16-pair dwords + att ----------
__global__ void k_pack_wet(const float* __restrict__ We, const float* __restrict__ att,
                           uint32_t* __restrict__ WeT, int C) {
    int t = blockIdx.x * blockDim.x + threadIdx.x;
    if (t >= C * 10) return;
    int c = t / 10, kk = t - c * 10;
    int g = c >> 2, j = c & 3;
    uint32_t v;
    if (kk < 9) v = packh2(We[(2 * kk) * C + c], We[(2 * kk + 1) * C + c]);
    else v = __float_as_uint(att[c]);
    WeT[g * 40 + j * 10 + kk] = v;
}

// ---------- combine Wl|Wr into padded Wc [K x NP], biases into bc [NP] ----------
__global__ void k_combine_w(const float* __restrict__ Wl, const float* __restrict__ bl,
                            const float* __restrict__ Wr, const float* __restrict__ br,
                            float* __restrict__ Wc, float* __restrict__ bc,
                            int K, int C, int NP) {
    int t = blockIdx.x * blockDim.x + threadIdx.x;
    if (t < K * NP) {
        int k = t / NP, n = t - k * NP;
        float v = 0.0f;
        if (n < C) v = Wl[k * C + n];
        else if (n < 2 * C) v = Wr[k * C + n - C];
        Wc[t] = v;
    }
    if (t < NP) {
        float v = 0.0f;
        if (t < C) v = bl[t];
        else if (t < 2 * C) v = br[t - C];
        bc[t] = v;
    }
}

// ---------- tiled dual GEMM: [NN x K] @ Wc[K x NP] -> xl|xr ----------
template <int KK, int NP, int C>
__global__ void __launch_bounds__(256)
k_gemm_dual(const float* __restrict__ A, const float* __restrict__ Wc,
            const float* __restrict__ bc, float* __restrict__ xl, float* __restrict__ xr) {
    constexpr int BM = 64, BN = 64, BK = 16;
    __shared__ float As[BK][BM];
    __shared__ float Ws[BK][BN];
    const int tidx = threadIdx.x;
    const int tx = tidx & 15;
    const int ty = tidx >> 4;
    const int m0 = blockIdx.x * BM;
    const int n0 = blockIdx.y * BN;

    float acc[4][4];
#pragma unroll
    for (int i2 = 0; i2 < 4; i2++)
#pragma unroll
        for (int j2 = 0; j2 < 4; j2++) acc[i2][j2] = 0.0f;

    for (int k0 = 0; k0 < KK; k0 += BK) {
        {
            int m = tidx >> 2;
            int kq = (tidx & 3) * 4;
            float4 v = make_float4(0.f, 0.f, 0.f, 0.f);
            if (m0 + m < NN && k0 + kq < KK)
                v = *(const float4*)(A + (size_t)(m0 + m) * KK + k0 + kq);
            As[kq + 0][m] = v.x; As[kq + 1][m] = v.y;
            As[kq + 2][m] = v.z; As[kq + 3][m] = v.w;
        }
        {
            int k = tidx >> 4;
            int nq = (tidx & 15) * 4;
            float4 v = make_float4(0.f, 0.f, 0.f, 0.f);
            if (k0 + k < KK)
                v = *(const float4*)(Wc + (size_t)(k0 + k) * NP + n0 + nq);
            *(float4*)&Ws[k][nq] = v;
        }
        __syncthreads();
#pragma unroll
        for (int k = 0; k < BK; k++) {
            float a[4], b[4];
            *(float4*)a = *(const float4*)&As[k][ty * 4];
            *(float4*)b = *(const float4*)&Ws[k][tx * 4];
#pragma unroll
            for (int i2 = 0; i2 < 4; i2++)
#pragma unroll
                for (int j2 = 0; j2 < 4; j2++) acc[i2][j2] += a[i2] * b[j2];
        }
        __syncthreads();
    }

    const int n = n0 + tx * 4;
    float4 bcv = *(const float4*)(bc + n);
#pragma unroll
    for (int i2 = 0; i2 < 4; i2++) {
        int m = m0 + ty * 4 + i2;
        if (m >= NN) continue;
        float4 o = make_float4(acc[i2][0] + bcv.x, acc[i2][1] + bcv.y,
                               acc[i2][2] + bcv.z, acc[i2][3] + bcv.w);
        if (n < C)            *(float4*)(xl + (size_t)m * C + n) = o;
        else if (n < 2 * C)   *(float4*)(xr + (size_t)m * C + n - C) = o;
    }
}

// ---------- edge-parallel scores: lane = csr position (incl. virtual self-loops) ----------
template <int C>
__global__ void __launch_bounds__(256)
k_score(const int* __restrict__ csr_src, const int* __restrict__ csr_dst,
        const uint32_t* __restrict__ eah2, const uint32_t* __restrict__ WeT,
        const float* __restrict__ xl, const float* __restrict__ xr,
        float* __restrict__ scores) {
    constexpr int G = C / 4;
    int pos = blockIdx.x * blockDim.x + threadIdx.x;
    if (pos >= ET) return;
    int s = csr_src[pos];
    int d = csr_dst[pos];

    uint32_t ean[9];
#pragma unroll
    for (int kk = 0; kk < 9; kk++) ean[kk] = eah2[(size_t)kk * ET + pos];

    const float* xls = xl + (size_t)s * C;
    const float* xrd = xr + (size_t)d * C;
    float4 xlc = *(const float4*)xls;
    float4 xrc = *(const float4*)xrd;
    float score = 0.0f;

#pragma unroll 2
    for (int g = 0; g < G; ++g) {
        float4 xln = make_float4(0.f, 0.f, 0.f, 0.f);
        float4 xrn = make_float4(0.f, 0.f, 0.f, 0.f);
        if (g + 1 < G) {
            xln = *(const float4*)(xls + 4 * (g + 1));
            xrn = *(const float4*)(xrd + 4 * (g + 1));
        }
        const uint32_t* wg = WeT + g * 40;   // uniform across wave -> scalar loads
        float lv[4] = {xlc.x, xlc.y, xlc.z, xlc.w};
        float rv[4] = {xrc.x, xrc.y, xrc.z, xrc.w};
#pragma unroll
        for (int j = 0; j < 4; j++) {
            float w = 0.0f;
#pragma unroll
            for (int kk = 0; kk < 9; kk++) w = fdot2u(ean[kk], wg[j * 10 + kk], w);
            float u = lv[j] + rv[j] + w;
            float h = fmaxf(u, NEG_SLOPE * u);
            score = fmaf(__uint_as_float(wg[j * 10 + 9]), h, score);
        }
        xlc = xln; xrc = xrn;
    }
    scores[pos] = score;
}

// ---------- per-node exact softmax + aggregation (wave per node) ----------
template <int VEC>
__device__ __forceinline__ void loadv(float* dstv, const float* p, bool act) {
    if (act) {
        if constexpr (VEC == 4) {
            float4 v = *(const float4*)p;
            dstv[0] = v.x; dstv[1] = v.y; dstv[2] = v.z; dstv[3] = v.w;
        } else {
            float2 v = *(const float2*)p;
            dstv[0] = v.x; dstv[1] = v.y;
        }
    } else {
#pragma unroll
        for (int j = 0; j < VEC; j++) dstv[j] = 0.f;
    }
}

template <int C, int VEC, int RELU>
__global__ void __launch_bounds__(256)
k_fin(const int* __restrict__ rowptr, const int* __restrict__ csr_src,
      const float* __restrict__ scores, const float* __restrict__ xl,
      const float* __restrict__ bias, float* __restrict__ out) {
    constexpr int NL = C / VEC;
    const int lane = threadIdx.x & 63;
    int wid = blockIdx.x * (blockDim.x >> 6) + (threadIdx.x >> 6);
    int nw = gridDim.x * (blockDim.x >> 6);
    const bool act = lane < NL;

    float bv[VEC];
    loadv<VEC>(bv, bias + lane * VEC, act);

    for (int i = wid; i < NN; i += nw) {
        int beg = __builtin_amdgcn_readfirstlane(rowptr[i]);
        int end = __builtin_amdgcn_readfirstlane(rowptr[i + 1]);
        float s_self = scores[EE + i];

        // pass 1: exact max over all edges incl. self-loop
        float m = s_self;
        for (int cs = beg; cs < end; cs += 64) {
            int cnt = end - cs; if (cnt > 64) cnt = 64;
            float sc = (lane < cnt) ? scores[cs + lane] : -INFINITY;
#pragma unroll
            for (int off = 32; off; off >>= 1) sc = fmaxf(sc, __shfl_xor(sc, off, 64));
            m = fmaxf(m, sc);
        }

        // self-loop contribution
        float xlv[VEC];
        loadv<VEC>(xlv, xl + (size_t)i * C + lane * VEC, act);
        float pes = __expf(s_self - m);
        float z = pes;
        float acc[VEC];
#pragma unroll
        for (int j = 0; j < VEC; j++) acc[j] = pes * xlv[j];

        // pass 2: exp, denom, weighted aggregation
        for (int cs = beg; cs < end; cs += 64) {
            int cnt = end - cs; if (cnt > 64) cnt = 64;
            float sc = (lane < cnt) ? scores[cs + lane] : -INFINITY;
            int srcl = (lane < cnt) ? csr_src[cs + lane] : 0;
            float pe = __expf(sc - m);          // -inf -> 0 for padding lanes
            float zc = pe;
#pragma unroll
            for (int off = 32; off; off >>= 1) zc += __shfl_xor(zc, off, 64);
            z += zc;

            // serial aggregation with depth-2 prefetch
            float xvA[VEC], xvB[VEC];
            if (cnt > 0) {
                int s0 = __builtin_amdgcn_readlane(srcl, 0);
                loadv<VEC>(xvA, xl + (size_t)s0 * C + lane * VEC, act);
            }
            if (cnt > 1) {
                int s1 = __builtin_amdgcn_readlane(srcl, 1);
                loadv<VEC>(xvB, xl + (size_t)s1 * C + lane * VEC, act);
            }
            for (int t = 0; t < cnt; t++) {
                float a = rlanef(pe, t);
                float cur[VEC];
#pragma unroll
                for (int j = 0; j < VEC; j++) { cur[j] = xvA[j]; xvA[j] = xvB[j]; }
                if (t + 2 < cnt) {
                    int sN = __builtin_amdgcn_readlane(srcl, t + 2);
                    loadv<VEC>(xvB, xl + (size_t)sN * C + lane * VEC, act);
                }
#pragma unroll
                for (int j = 0; j < VEC; j++) acc[j] = fmaf(a, cur[j], acc[j]);
            }
        }

        float rz = 1.0f / z;
        if (act) {
            float o[VEC];
#pragma unroll
            for (int j = 0; j < VEC; j++) {
                o[j] = acc[j] * rz + bv[j];
                if (RELU) o[j] = fmaxf(o[j], 0.0f);
            }
            if constexpr (VEC == 4) {
                *(float4*)(out + (size_t)i * C + lane * 4) = make_float4(o[0], o[1], o[2], o[3]);
            } else {
                *(float2*)(out + (size_t)i * C + lane * 2) = make_float2(o[0], o[1]);
            }
        }
    }
}

// ---------- mean pooling per graph (batch_ids sorted); relu folded in ----------
__global__ void k_pool(const float* __restrict__ h, const int* __restrict__ batch,
                       float* __restrict__ pooled) {
    int g = blockIdx.x;
    int lo = 0, hi = NN;
    while (lo < hi) { int mid = (lo + hi) >> 1; if (batch[mid] < g) lo = mid + 1; else hi = mid; }
    int start = lo;
    lo = start; hi = NN;
    while (lo < hi) { int mid = (lo + hi) >> 1; if (batch[mid] < g + 1) lo = mid + 1; else hi = mid; }
    int end = lo;
    float cnt = (float)(end - start);
    int c = threadIdx.x;
    if (c < 200) {
        float acc = 0.0f;
        for (int i = start; i < end; i++) acc += fmaxf(h[(size_t)i * 200 + c], 0.0f);
        pooled[g * 200 + c] = acc / fmaxf(cnt, 1.0f);
    }
}

// ---------- small dense layers on [G, *] ----------
__global__ void k_mlp(const float* __restrict__ X, const float* __restrict__ W,
                      const float* __restrict__ b, float* __restrict__ Y,
                      int Cin, int Cout, int do_relu) {
    int t = blockIdx.x * blockDim.x + threadIdx.x;
    if (t >= GG * Cout) return;
    int g = t / Cout, j = t - g * Cout;
    const float* xrow = X + (size_t)g * Cin;
    float acc = b[j];
    for (int k = 0; k < Cin; k++) acc += xrow[k] * W[k * Cout + j];
    if (do_relu) acc = fmaxf(acc, 0.0f);
    Y[t] = acc;
}

extern "C" void kernel_launch(void* const* d_in, const int* in_sizes, int n_in,
                              void* d_out, int out_size, void* d_ws, size_t ws_size,
                              hipStream_t stream) {
    const float* x   = (const float*)d_in[0];
    const int*   ei  = (const int*)d_in[1];
    const float* ea  = (const float*)d_in[2];
    const int*   bat = (const int*)d_in[3];
    const float* W1l = (const float*)d_in[4];  const float* b1l = (const float*)d_in[5];
    const float* W1r = (const float*)d_in[6];  const float* b1r = (const float*)d_in[7];
    const float* W1e = (const float*)d_in[8];
    const float* a1  = (const float*)d_in[9];  const float* c1  = (const float*)d_in[10];
    const float* W2l = (const float*)d_in[11]; const float* b2l = (const float*)d_in[12];
    const float* W2r = (const float*)d_in[13]; const float* b2r = (const float*)d_in[14];
    const float* W2e = (const float*)d_in[15];
    const float* a2  = (const float*)d_in[16]; const float* c2  = (const float*)d_in[17];
    const float* W3  = (const float*)d_in[18]; const float* b3  = (const float*)d_in[19];
    const float* F1  = (const float*)d_in[20]; const float* bf1 = (const float*)d_in[21];
    const float* F2  = (const float*)d_in[22]; const float* bf2 = (const float*)d_in[23];
    const float* F3  = (const float*)d_in[24]; const float* bf3 = (const float*)d_in[25];

    const int* srcv = ei;        // edge_index[0]
    const int* dstv = ei + EE;   // edge_index[1]

    float* W = (float*)d_ws;
    size_t off = 0;
    int*      hist    = (int*)(W + off); off += NN;
    float*    xl      = W + off; off += (size_t)NN * 200;
    float*    xr      = W + off; off += (size_t)NN * 200;
    float*    h1      = W + off; off += (size_t)NN * 100;
    float*    h2      = W + off; off += (size_t)NN * 200;
    int*      rowptr  = (int*)(W + off); off += NN + 4;
    int*      cursor  = (int*)(W + off); off += NN;
    int*      bsum    = (int*)(W + off); off += 256;
    // union: csr_eid (first EE ints, used only pre-score) / scores (ET floats)
    int*      csr_eid = (int*)(W + off);
    float*    scores  = (float*)(W + off); off += ET;
    int*      csr_src = (int*)(W + off); off += ET;
    int*      csr_dst = (int*)(W + off); off += ET;
    uint32_t* eah2    = (uint32_t*)(W + off); off += (size_t)9 * ET;
    uint32_t* WeT1    = (uint32_t*)(W + off); off += 25 * 40;
    uint32_t* WeT2    = (uint32_t*)(W + off); off += 50 * 40;
    float*    Wc1     = W + off; off += 16 * 256;
    float*    bc1     = W + off; off += 256;
    float*    Wc2     = W + off; off += 100 * 448;
    float*    bc2     = W + off; off += 448;
    float*    pooled  = W + off; off += (size_t)GG * 200;
    float*    p400    = W + off; off += (size_t)GG * 400;
    float*    y1      = W + off; off += (size_t)GG * 200;
    float*    y2      = W + off; off += (size_t)GG * 100;
    (void)ws_size; (void)n_in; (void)in_sizes; (void)out_size;

    const int B = 256;
    const int NODEB = 12500;   // 4 waves/block -> 50000 waves, 1 node each

    // ---- degree histogram + CSR by dst (real edges only) ----
    hipMemsetAsync(hist, 0, (size_t)NN * sizeof(int), stream);
    k_hist<<<(EE + B - 1) / B, B, 0, stream>>>(dstv, hist);
    k_scan_a<<<NB, 256, 0, stream>>>(hist, bsum);
    k_scan_b<<<1, 1, 0, stream>>>(bsum, rowptr);
    k_scan_c<<<NB, 256, 0, stream>>>(hist, bsum, rowptr);
    k_cursor_init<<<(NN + B - 1) / B, B, 0, stream>>>(rowptr, cursor);
    k_scatter<<<(EE + B - 1) / B, B, 0, stream>>>(dstv, cursor, csr_eid, csr_dst);

    // ---- csr-ordered src + fp16 SoA edge-attr + virtual self-loop edges ----
    k_csr_src<<<(EE + B - 1) / B, B, 0, stream>>>(csr_eid, srcv, csr_src);
    k_pack2<<<(EE + B - 1) / B, B, 0, stream>>>(csr_eid, ea, eah2);
    k_loop<<<NODEB, B, 0, stream>>>(rowptr, eah2, csr_src, csr_dst);

    // ---- weight prep ----
    k_pack_wet<<<(100 * 10 + B - 1) / B, B, 0, stream>>>(W1e, a1, WeT1, 100);
    k_pack_wet<<<(200 * 10 + B - 1) / B, B, 0, stream>>>(W2e, a2, WeT2, 200);
    k_combine_w<<<(16 * 256 + B - 1) / B, B, 0, stream>>>(W1l, b1l, W1r, b1r, Wc1, bc1, 16, 100, 256);
    k_combine_w<<<(100 * 448 + B - 1) / B, B, 0, stream>>>(W2l, b2l, W2r, b2r, Wc2, bc2, 100, 200, 448);

    // NOTE: from here on, scores overwrites csr_eid (dead after pack kernels).

    // ---- GAT layer 1: 16 -> 100 ----
    {
        dim3 grid((NN + 63) / 64, 256 / 64);
        k_gemm_dual<16, 256, 100><<<grid, 256, 0, stream>>>(x, Wc1, bc1, xl, xr);
    }
    k_score<100><<<(ET + B - 1) / B, B, 0, stream>>>(csr_src, csr_dst, eah2, WeT1, xl, xr, scores);
    k_fin<100, 2, 1><<<NODEB, B, 0, stream>>>(rowptr, csr_src, scores, xl, c1, h1);

    // ---- GAT layer 2: 100 -> 200 ----
    {
        dim3 grid((NN + 63) / 64, 448 / 64);
        k_gemm_dual<100, 448, 200><<<grid, 256, 0, stream>>>(h1, Wc2, bc2, xl, xr);
    }
    k_score<200><<<(ET + B - 1) / B, B, 0, stream>>>(csr_src, csr_dst, eah2, WeT2, xl, xr, scores);
    k_fin<200, 4, 0><<<NODEB, B, 0, stream>>>(rowptr, csr_src, scores, xl, c2, h2);

    // ---- pool (mean over graph, relu fused) then W3 + FFN ----
    k_pool<<<GG, 256, 0, stream>>>(h2, bat, pooled);
    k_mlp<<<(GG * 400 + B - 1) / B, B, 0, stream>>>(pooled, W3, b3, p400, 200, 400, 0);
    k_mlp<<<(GG * 200 + B - 1) / B, B, 0, stream>>>(p400, F1, bf1, y1, 400, 200, 1);
    k_mlp<<<(GG * 100 + B - 1) / B, B, 0, stream>>>(y1, F2, bf2, y2, 200, 100, 1);
    k_mlp<<<(GG * 100 + B - 1) / B, B, 0, stream>>>(y2, F3, bf3, (float*)d_out, 100, 100, 0);
}

// Round 2
// 1622.637 us; speedup vs baseline: 1.2099x; 1.2099x over previous
//
#include <hip/hip_runtime.h>
#include <cstdint>
#include <climits>
#include <math.h>

#define NN 50000
#define EE 1600000
#define ET (EE + NN)   // real edges + one self-loop per node
#define GG 512
#define NEG_SLOPE 0.2f
#define NB 196          // ceil(NN/256) scan blocks

typedef _Float16 half2v __attribute__((ext_vector_type(2)));

__device__ __forceinline__ uint32_t packh2(float a, float b) {
    union { half2v h; uint32_t u; } c;
    c.h = half2v{(_Float16)a, (_Float16)b};
    return c.u;
}
__device__ __forceinline__ float2 uph(uint32_t u) {
    union { uint32_t u; half2v h; } c;
    c.u = u;
    return make_float2((float)c.h.x, (float)c.h.y);
}
__device__ __forceinline__ float fdot2u(uint32_t a, uint32_t b, float c) {
    union { uint32_t u; half2v h; } ua, ub;
    ua.u = a; ub.u = b;
    return __builtin_amdgcn_fdot2(ua.h, ub.h, c, false);
}
__device__ __forceinline__ float rlanef(float v, int l) {
    return __int_as_float(__builtin_amdgcn_readlane(__float_as_int(v), l));
}

// ---------- degree histogram ----------
__global__ void k_hist(const int* __restrict__ dst, int* __restrict__ hist) {
    int e = blockIdx.x * blockDim.x + threadIdx.x;
    if (e < EE) atomicAdd(&hist[dst[e]], 1);
}

// ---------- CSR build ----------
__global__ void k_scan_a(const int* __restrict__ hist, int* __restrict__ bsum) {
    __shared__ int tmp[256];
    int i = blockIdx.x * 256 + threadIdx.x;
    tmp[threadIdx.x] = (i < NN) ? hist[i] : 0;
    __syncthreads();
    for (int d = 128; d; d >>= 1) {
        if (threadIdx.x < d) tmp[threadIdx.x] += tmp[threadIdx.x + d];
        __syncthreads();
    }
    if (threadIdx.x == 0) bsum[blockIdx.x] = tmp[0];
}

// parallel single-block scan over NB block sums (was a serial 196-iter loop)
__global__ void k_scan_b(int* __restrict__ bsum, int* __restrict__ rowptr) {
    __shared__ int tmp[256];
    int t = threadIdx.x;
    int v = (t < NB) ? bsum[t] : 0;
    tmp[t] = v;
    __syncthreads();
    for (int d = 1; d < 256; d <<= 1) {
        int u = (t >= d) ? tmp[t - d] : 0;
        __syncthreads();
        tmp[t] += u;
        __syncthreads();
    }
    if (t < NB) bsum[t] = tmp[t] - v;        // exclusive
    if (t == 255) rowptr[NN] = tmp[255];     // total == EE
}

__global__ void k_scan_c(const int* __restrict__ hist, const int* __restrict__ bsum,
                         int* __restrict__ rowptr) {
    __shared__ int tmp[256];
    int i = blockIdx.x * 256 + threadIdx.x;
    int v = (i < NN) ? hist[i] : 0;
    tmp[threadIdx.x] = v;
    __syncthreads();
    for (int d = 1; d < 256; d <<= 1) {
        int t = (threadIdx.x >= d) ? tmp[threadIdx.x - d] : 0;
        __syncthreads();
        tmp[threadIdx.x] += t;
        __syncthreads();
    }
    if (i < NN) rowptr[i] = tmp[threadIdx.x] - v + bsum[blockIdx.x];
}

__global__ void k_cursor_init(const int* __restrict__ rowptr, int* __restrict__ cursor) {
    int i = blockIdx.x * blockDim.x + threadIdx.x;
    if (i < NN) cursor[i] = rowptr[i];
}

__global__ void k_scatter(const int* __restrict__ dst, int* __restrict__ cursor,
                          int* __restrict__ csr_eid, int* __restrict__ csr_dst) {
    int e = blockIdx.x * blockDim.x + threadIdx.x;
    if (e < EE) {
        int d = dst[e];
        int p = atomicAdd(&cursor[d], 1);
        csr_eid[p] = e;
        csr_dst[p] = d;
    }
}

__global__ void k_csr_src(const int* __restrict__ csr_eid, const int* __restrict__ srcv,
                          int* __restrict__ csr_src) {
    int p = blockIdx.x * blockDim.x + threadIdx.x;
    if (p < EE) csr_src[p] = srcv[csr_eid[p]];
}

// ---------- pack ea rows to fp16 AoS (12 dwords, 9 used) in CSR order ----------
__global__ void k_pack_ea2(const int* __restrict__ csr_eid, const float* __restrict__ ea,
                           uint32_t* __restrict__ eaa) {
    int pos = blockIdx.x * blockDim.x + threadIdx.x;
    if (pos >= EE) return;
    int e = csr_eid[pos];
    const float* r = ea + (size_t)e * 18;
    uint32_t o[12];
#pragma unroll
    for (int kk = 0; kk < 9; kk++) {
        float2 q = *(const float2*)(r + 2 * kk);
        o[kk] = packh2(q.x, q.y);
    }
    o[9] = o[10] = o[11] = 0;
    uint4* dst = (uint4*)(eaa + (size_t)pos * 12);
    dst[0] = *(uint4*)&o[0];
    dst[1] = *(uint4*)&o[4];
    dst[2] = *(uint4*)&o[8];
}

// ---------- self-loop edge attr = mean of incoming ea; append virtual edges ----------
__global__ void __launch_bounds__(256)
k_loop2(const int* __restrict__ rowptr, uint32_t* __restrict__ eaa,
        int* __restrict__ csr_src, int* __restrict__ csr_dst) {
    const int lane = threadIdx.x & 63;
    int wid = blockIdx.x * (blockDim.x >> 6) + (threadIdx.x >> 6);
    int nw = gridDim.x * (blockDim.x >> 6);

    for (int i = wid; i < NN; i += nw) {
        int beg = __builtin_amdgcn_readfirstlane(rowptr[i]);
        int end = __builtin_amdgcn_readfirstlane(rowptr[i + 1]);
        float s[18];
#pragma unroll
        for (int j = 0; j < 18; j++) s[j] = 0.f;
        for (int cs = beg; cs < end; cs += 64) {
            int cnt = end - cs; if (cnt > 64) cnt = 64;
            if (lane < cnt) {
                const uint32_t* pe = eaa + (size_t)(cs + lane) * 12;
                uint4 a = *(const uint4*)pe;
                uint4 b = *(const uint4*)(pe + 4);
                uint32_t c = pe[8];
                uint32_t w[9] = {a.x, a.y, a.z, a.w, b.x, b.y, b.z, b.w, c};
#pragma unroll
                for (int kk = 0; kk < 9; kk++) {
                    float2 q = uph(w[kk]);
                    s[2 * kk] += q.x; s[2 * kk + 1] += q.y;
                }
            }
        }
#pragma unroll
        for (int j = 0; j < 18; j++) {
#pragma unroll
            for (int off = 32; off; off >>= 1) s[j] += __shfl_xor(s[j], off, 64);
        }
        if (lane == 0) {
            int deg = end - beg;
            float rd = (deg > 0) ? 1.0f / (float)deg : 0.0f;
            uint32_t o[12];
#pragma unroll
            for (int kk = 0; kk < 9; kk++) o[kk] = packh2(s[2 * kk] * rd, s[2 * kk + 1] * rd);
            o[9] = o[10] = o[11] = 0;
            uint4* dst = (uint4*)(eaa + (size_t)(EE + i) * 12);
            dst[0] = *(uint4*)&o[0];
            dst[1] = *(uint4*)&o[4];
            dst[2] = *(uint4*)&o[8];
            csr_src[EE + i] = i; csr_dst[EE + i] = i;
        }
    }
}

// ---------- pack WeT: group g = 4 features; per feature: 9 fp16-pair dwords + att ----------
__global__ void k_pack_wet(const float* __restrict__ We, const float* __restrict__ att,
                           uint32_t* __restrict__ WeT, int C) {
    int t = blockIdx.x * blockDim.x + threadIdx.x;
    if (t >= C * 10) return;
    int c = t / 10, kk = t - c * 10;
    int g = c >> 2, j = c & 3;
    uint32_t v;
    if (kk < 9) v = packh2(We[(2 * kk) * C + c], We[(2 * kk + 1) * C + c]);
    else v = __float_as_uint(att[c]);
    WeT[g * 40 + j * 10 + kk] = v;
}

// ---------- combine Wl|Wr into padded Wc [K x NP], biases into bc [NP] ----------
__global__ void k_combine_w(const float* __restrict__ Wl, const float* __restrict__ bl,
                            const float* __restrict__ Wr, const float* __restrict__ br,
                            float* __restrict__ Wc, float* __restrict__ bc,
                            int K, int C, int NP) {
    int t = blockIdx.x * blockDim.x + threadIdx.x;
    if (t < K * NP) {
        int k = t / NP, n = t - k * NP;
        float v = 0.0f;
        if (n < C) v = Wl[k * C + n];
        else if (n < 2 * C) v = Wr[k * C + n - C];
        Wc[t] = v;
    }
    if (t < NP) {
        float v = 0.0f;
        if (t < C) v = bl[t];
        else if (t < 2 * C) v = br[t - C];
        bc[t] = v;
    }
}

// ---------- tiled dual GEMM -> xl (fp32) + xl16/xr16 (packed fp16, padded pitch RL) ----
template <int KK, int NP, int C, int RL>
__global__ void __launch_bounds__(256)
k_gemm_dual(const float* __restrict__ A, const float* __restrict__ Wc,
            const float* __restrict__ bc, float* __restrict__ xl,
            uint32_t* __restrict__ xl16, uint32_t* __restrict__ xr16) {
    constexpr int BM = 64, BN = 64, BK = 16;
    __shared__ float As[BK][BM];
    __shared__ float Ws[BK][BN];
    const int tidx = threadIdx.x;
    const int tx = tidx & 15;
    const int ty = tidx >> 4;
    const int m0 = blockIdx.x * BM;
    const int n0 = blockIdx.y * BN;

    float acc[4][4];
#pragma unroll
    for (int i2 = 0; i2 < 4; i2++)
#pragma unroll
        for (int j2 = 0; j2 < 4; j2++) acc[i2][j2] = 0.0f;

    for (int k0 = 0; k0 < KK; k0 += BK) {
        {
            int m = tidx >> 2;
            int kq = (tidx & 3) * 4;
            float4 v = make_float4(0.f, 0.f, 0.f, 0.f);
            if (m0 + m < NN && k0 + kq < KK)
                v = *(const float4*)(A + (size_t)(m0 + m) * KK + k0 + kq);
            As[kq + 0][m] = v.x; As[kq + 1][m] = v.y;
            As[kq + 2][m] = v.z; As[kq + 3][m] = v.w;
        }
        {
            int k = tidx >> 4;
            int nq = (tidx & 15) * 4;
            float4 v = make_float4(0.f, 0.f, 0.f, 0.f);
            if (k0 + k < KK)
                v = *(const float4*)(Wc + (size_t)(k0 + k) * NP + n0 + nq);
            *(float4*)&Ws[k][nq] = v;
        }
        __syncthreads();
#pragma unroll
        for (int k = 0; k < BK; k++) {
            float a[4], b[4];
            *(float4*)a = *(const float4*)&As[k][ty * 4];
            *(float4*)b = *(const float4*)&Ws[k][tx * 4];
#pragma unroll
            for (int i2 = 0; i2 < 4; i2++)
#pragma unroll
                for (int j2 = 0; j2 < 4; j2++) acc[i2][j2] += a[i2] * b[j2];
        }
        __syncthreads();
    }

    const int n = n0 + tx * 4;
    float4 bcv = *(const float4*)(bc + n);
#pragma unroll
    for (int i2 = 0; i2 < 4; i2++) {
        int m = m0 + ty * 4 + i2;
        if (m >= NN) continue;
        float4 o = make_float4(acc[i2][0] + bcv.x, acc[i2][1] + bcv.y,
                               acc[i2][2] + bcv.z, acc[i2][3] + bcv.w);
        uint2 p;
        p.x = packh2(o.x, o.y);
        p.y = packh2(o.z, o.w);
        if (n < C) {
            *(float4*)(xl + (size_t)m * C + n) = o;
            *(uint2*)(xl16 + (size_t)m * RL + n / 2) = p;
        } else if (n < 2 * C) {
            *(uint2*)(xr16 + (size_t)m * RL + (n - C) / 2) = p;
        }
    }
}

// ---------- edge-parallel scores: full fp16 rows preloaded upfront (max MLP) ----------
template <int C>
__global__ void __launch_bounds__(256, 1)
k_score(const int* __restrict__ csr_src, const int* __restrict__ csr_dst,
        const uint32_t* __restrict__ eaa, const uint32_t* __restrict__ WeT,
        const uint32_t* __restrict__ xl16, const uint32_t* __restrict__ xr16,
        float* __restrict__ scores) {
    constexpr int RL = ((C / 2) + 3) & ~3;   // padded dwords per row
    int pos = blockIdx.x * blockDim.x + threadIdx.x;
    if (pos >= ET) return;
    int s = csr_src[pos];
    int d = csr_dst[pos];

    // issue ALL row loads before any compute: ~7 (C=100) / 13 (C=200) lines
    // in flight per thread per operand
    uint32_t lw[RL], rw[RL];
    const uint4* pl = (const uint4*)(xl16 + (size_t)s * RL);
    const uint4* pr = (const uint4*)(xr16 + (size_t)d * RL);
#pragma unroll
    for (int i = 0; i < RL / 4; i++) *(uint4*)&lw[4 * i] = pl[i];
#pragma unroll
    for (int i = 0; i < RL / 4; i++) *(uint4*)&rw[4 * i] = pr[i];

    const uint32_t* pe = eaa + (size_t)pos * 12;
    uint4 e0 = *(const uint4*)pe;
    uint4 e1 = *(const uint4*)(pe + 4);
    uint32_t e8 = pe[8];
    uint32_t ean[9] = {e0.x, e0.y, e0.z, e0.w, e1.x, e1.y, e1.z, e1.w, e8};

    float score = 0.0f;
#pragma unroll
    for (int g = 0; g < C / 4; g++) {
        const uint32_t* wg = WeT + g * 40;   // wave-uniform -> scalar loads
        float2 l0 = uph(lw[2 * g]), l1 = uph(lw[2 * g + 1]);
        float2 r0 = uph(rw[2 * g]), r1 = uph(rw[2 * g + 1]);
        float lv[4] = {l0.x, l0.y, l1.x, l1.y};
        float rv[4] = {r0.x, r0.y, r1.x, r1.y};
#pragma unroll
        for (int j = 0; j < 4; j++) {
            float w = 0.0f;
#pragma unroll
            for (int kk = 0; kk < 9; kk++) w = fdot2u(ean[kk], wg[j * 10 + kk], w);
            float u = lv[j] + rv[j] + w;
            float h = fmaxf(u, NEG_SLOPE * u);
            score = fmaf(__uint_as_float(wg[j * 10 + 9]), h, score);
        }
    }
    scores[pos] = score;
}

// ---------- per-node exact softmax + aggregation (wave per node) ----------
template <int VEC>
__device__ __forceinline__ void loadv(float* dstv, const float* p, bool act) {
    if (act) {
        if constexpr (VEC == 4) {
            float4 v = *(const float4*)p;
            dstv[0] = v.x; dstv[1] = v.y; dstv[2] = v.z; dstv[3] = v.w;
        } else {
            float2 v = *(const float2*)p;
            dstv[0] = v.x; dstv[1] = v.y;
        }
    } else {
#pragma unroll
        for (int j = 0; j < VEC; j++) dstv[j] = 0.f;
    }
}

template <int C, int VEC, int RELU>
__global__ void __launch_bounds__(256)
k_fin(const int* __restrict__ rowptr, const int* __restrict__ csr_src,
      const float* __restrict__ scores, const float* __restrict__ xl,
      const float* __restrict__ bias, float* __restrict__ out) {
    constexpr int NL = C / VEC;
    const int lane = threadIdx.x & 63;
    int wid = blockIdx.x * (blockDim.x >> 6) + (threadIdx.x >> 6);
    int nw = gridDim.x * (blockDim.x >> 6);
    const bool act = lane < NL;

    float bv[VEC];
    loadv<VEC>(bv, bias + lane * VEC, act);

    for (int i = wid; i < NN; i += nw) {
        int beg = __builtin_amdgcn_readfirstlane(rowptr[i]);
        int end = __builtin_amdgcn_readfirstlane(rowptr[i + 1]);
        float s_self = scores[EE + i];

        // pass 1: exact max
        float m = s_self;
        for (int cs = beg; cs < end; cs += 64) {
            int cnt = end - cs; if (cnt > 64) cnt = 64;
            float sc = (lane < cnt) ? scores[cs + lane] : -INFINITY;
#pragma unroll
            for (int off = 32; off; off >>= 1) sc = fmaxf(sc, __shfl_xor(sc, off, 64));
            m = fmaxf(m, sc);
        }

        float xlv[VEC];
        loadv<VEC>(xlv, xl + (size_t)i * C + lane * VEC, act);
        float pes = __expf(s_self - m);
        float z = pes;
        float acc[VEC];
#pragma unroll
        for (int j = 0; j < VEC; j++) acc[j] = pes * xlv[j];

        // pass 2: exp + denom + aggregation (8-deep prefetch, named buffers)
        for (int cs = beg; cs < end; cs += 64) {
            int cnt = end - cs; if (cnt > 64) cnt = 64;
            float sc = (lane < cnt) ? scores[cs + lane] : -INFINITY;
            int srcl = (lane < cnt) ? csr_src[cs + lane] : 0;
            float pe = __expf(sc - m);
            float zc = pe;
#pragma unroll
            for (int off = 32; off; off >>= 1) zc += __shfl_xor(zc, off, 64);
            z += zc;

            float A[4][VEC], Bv[4][VEC];
            auto LD4 = [&](float (&buf)[4][VEC], int t0) {
#pragma unroll
                for (int q = 0; q < 4; q++) {
                    int t = t0 + q;
                    if (t < cnt) {
                        int sx = __builtin_amdgcn_readlane(srcl, t);
                        loadv<VEC>(buf[q], xl + (size_t)sx * C + lane * VEC, act);
                    }
                }
            };
            auto USE4 = [&](float (&buf)[4][VEC], int t0) {
#pragma unroll
                for (int q = 0; q < 4; q++) {
                    int t = t0 + q;
                    if (t < cnt) {
                        float a = rlanef(pe, t);
#pragma unroll
                        for (int j = 0; j < VEC; j++) acc[j] = fmaf(a, buf[q][j], acc[j]);
                    }
                }
            };
            LD4(A, 0);
            for (int t0 = 0; t0 < cnt; t0 += 8) {
                if (t0 + 4 < cnt) LD4(Bv, t0 + 4);
                USE4(A, t0);
                if (t0 + 8 < cnt) LD4(A, t0 + 8);
                USE4(Bv, t0 + 4);
            }
        }

        float rz = 1.0f / z;
        if (act) {
            float o[VEC];
#pragma unroll
            for (int j = 0; j < VEC; j++) {
                o[j] = acc[j] * rz + bv[j];
                if (RELU) o[j] = fmaxf(o[j], 0.0f);
            }
            if constexpr (VEC == 4) {
                *(float4*)(out + (size_t)i * C + lane * 4) = make_float4(o[0], o[1], o[2], o[3]);
            } else {
                *(float2*)(out + (size_t)i * C + lane * 2) = make_float2(o[0], o[1]);
            }
        }
    }
}

// ---------- mean pooling per graph (batch_ids sorted); relu folded in ----------
__global__ void k_pool(const float* __restrict__ h, const int* __restrict__ batch,
                       float* __restrict__ pooled) {
    int g = blockIdx.x;
    int lo = 0, hi = NN;
    while (lo < hi) { int mid = (lo + hi) >> 1; if (batch[mid] < g) lo = mid + 1; else hi = mid; }
    int start = lo;
    lo = start; hi = NN;
    while (lo < hi) { int mid = (lo + hi) >> 1; if (batch[mid] < g + 1) lo = mid + 1; else hi = mid; }
    int end = lo;
    float cnt = (float)(end - start);
    int c = threadIdx.x;
    if (c < 200) {
        float acc = 0.0f;
        for (int i = start; i < end; i++) acc += fmaxf(h[(size_t)i * 200 + c], 0.0f);
        pooled[g * 200 + c] = acc / fmaxf(cnt, 1.0f);
    }
}

// ---------- small dense layers on [G, *] ----------
__global__ void k_mlp(const float* __restrict__ X, const float* __restrict__ W,
                      const float* __restrict__ b, float* __restrict__ Y,
                      int Cin, int Cout, int do_relu) {
    int t = blockIdx.x * blockDim.x + threadIdx.x;
    if (t >= GG * Cout) return;
    int g = t / Cout, j = t - g * Cout;
    const float* xrow = X + (size_t)g * Cin;
    float acc = b[j];
    for (int k = 0; k < Cin; k++) acc += xrow[k] * W[k * Cout + j];
    if (do_relu) acc = fmaxf(acc, 0.0f);
    Y[t] = acc;
}

extern "C" void kernel_launch(void* const* d_in, const int* in_sizes, int n_in,
                              void* d_out, int out_size, void* d_ws, size_t ws_size,
                              hipStream_t stream) {
    const float* x   = (const float*)d_in[0];
    const int*   ei  = (const int*)d_in[1];
    const float* ea  = (const float*)d_in[2];
    const int*   bat = (const int*)d_in[3];
    const float* W1l = (const float*)d_in[4];  const float* b1l = (const float*)d_in[5];
    const float* W1r = (const float*)d_in[6];  const float* b1r = (const float*)d_in[7];
    const float* W1e = (const float*)d_in[8];
    const float* a1  = (const float*)d_in[9];  const float* c1  = (const float*)d_in[10];
    const float* W2l = (const float*)d_in[11]; const float* b2l = (const float*)d_in[12];
    const float* W2r = (const float*)d_in[13]; const float* b2r = (const float*)d_in[14];
    const float* W2e = (const float*)d_in[15];
    const float* a2  = (const float*)d_in[16]; const float* c2  = (const float*)d_in[17];
    const float* W3  = (const float*)d_in[18]; const float* b3  = (const float*)d_in[19];
    const float* F1  = (const float*)d_in[20]; const float* bf1 = (const float*)d_in[21];
    const float* F2  = (const float*)d_in[22]; const float* bf2 = (const float*)d_in[23];
    const float* F3  = (const float*)d_in[24]; const float* bf3 = (const float*)d_in[25];

    const int* srcv = ei;        // edge_index[0]
    const int* dstv = ei + EE;   // edge_index[1]

    float* W = (float*)d_ws;
    size_t off = 0;
    int*      hist    = (int*)(W + off); off += NN;
    float*    xl      = W + off; off += (size_t)NN * 200;
    float*    h1      = W + off; off += (size_t)NN * 100;
    float*    h2      = W + off; off += (size_t)NN * 200;
    int*      rowptr  = (int*)(W + off); off += NN + 4;
    int*      cursor  = (int*)(W + off); off += NN;
    int*      bsum    = (int*)(W + off); off += 256;
    // union: csr_eid (first EE ints, dead after k_pack_ea2) / scores (ET floats)
    int*      csr_eid = (int*)(W + off);
    float*    scores  = (float*)(W + off); off += ET;
    int*      csr_src = (int*)(W + off); off += ET;
    int*      csr_dst = (int*)(W + off); off += ET;
    uint32_t* eaa     = (uint32_t*)(W + off); off += (size_t)ET * 12;
    uint32_t* xl16    = (uint32_t*)(W + off); off += (size_t)NN * 100;
    uint32_t* xr16    = (uint32_t*)(W + off); off += (size_t)NN * 100;
    uint32_t* WeT1    = (uint32_t*)(W + off); off += 25 * 40;
    uint32_t* WeT2    = (uint32_t*)(W + off); off += 50 * 40;
    float*    Wc1     = W + off; off += 16 * 256;
    float*    bc1     = W + off; off += 256;
    float*    Wc2     = W + off; off += 100 * 448;
    float*    bc2     = W + off; off += 448;
    float*    pooled  = W + off; off += (size_t)GG * 200;
    float*    p400    = W + off; off += (size_t)GG * 400;
    float*    y1      = W + off; off += (size_t)GG * 200;
    float*    y2      = W + off; off += (size_t)GG * 100;
    (void)ws_size; (void)n_in; (void)in_sizes; (void)out_size;

    const int B = 256;
    const int NODEB = 12500;   // 4 waves/block -> 50000 waves, 1 node each

    // ---- degree histogram + CSR by dst (real edges only) ----
    hipMemsetAsync(hist, 0, (size_t)NN * sizeof(int), stream);
    k_hist<<<(EE + B - 1) / B, B, 0, stream>>>(dstv, hist);
    k_scan_a<<<NB, 256, 0, stream>>>(hist, bsum);
    k_scan_b<<<1, 256, 0, stream>>>(bsum, rowptr);
    k_scan_c<<<NB, 256, 0, stream>>>(hist, bsum, rowptr);
    k_cursor_init<<<(NN + B - 1) / B, B, 0, stream>>>(rowptr, cursor);
    k_scatter<<<(EE + B - 1) / B, B, 0, stream>>>(dstv, cursor, csr_eid, csr_dst);

    // ---- csr-ordered src + fp16 AoS edge-attr + virtual self-loop edges ----
    k_csr_src<<<(EE + B - 1) / B, B, 0, stream>>>(csr_eid, srcv, csr_src);
    k_pack_ea2<<<(EE + B - 1) / B, B, 0, stream>>>(csr_eid, ea, eaa);
    k_loop2<<<NODEB, B, 0, stream>>>(rowptr, eaa, csr_src, csr_dst);

    // ---- weight prep ----
    k_pack_wet<<<(100 * 10 + B - 1) / B, B, 0, stream>>>(W1e, a1, WeT1, 100);
    k_pack_wet<<<(200 * 10 + B - 1) / B, B, 0, stream>>>(W2e, a2, WeT2, 200);
    k_combine_w<<<(16 * 256 + B - 1) / B, B, 0, stream>>>(W1l, b1l, W1r, b1r, Wc1, bc1, 16, 100, 256);
    k_combine_w<<<(100 * 448 + B - 1) / B, B, 0, stream>>>(W2l, b2l, W2r, b2r, Wc2, bc2, 100, 200, 448);

    // NOTE: from here on, scores overwrites csr_eid (dead).

    // ---- GAT layer 1: 16 -> 100 (RL = 52) ----
    {
        dim3 grid((NN + 63) / 64, 256 / 64);
        k_gemm_dual<16, 256, 100, 52><<<grid, 256, 0, stream>>>(x, Wc1, bc1, xl, xl16, xr16);
    }
    k_score<100><<<(ET + B - 1) / B, B, 0, stream>>>(csr_src, csr_dst, eaa, WeT1, xl16, xr16, scores);
    k_fin<100, 2, 1><<<NODEB, B, 0, stream>>>(rowptr, csr_src, scores, xl, c1, h1);

    // ---- GAT layer 2: 100 -> 200 (RL = 100) ----
    {
        dim3 grid((NN + 63) / 64, 448 / 64);
        k_gemm_dual<100, 448, 200, 100><<<grid, 256, 0, stream>>>(h1, Wc2, bc2, xl, xl16, xr16);
    }
    k_score<200><<<(ET + B - 1) / B, B, 0, stream>>>(csr_src, csr_dst, eaa, WeT2, xl16, xr16, scores);
    k_fin<200, 4, 0><<<NODEB, B, 0, stream>>>(rowptr, csr_src, scores, xl, c2, h2);

    // ---- pool (mean over graph, relu fused) then W3 + FFN ----
    k_pool<<<GG, 256, 0, stream>>>(h2, bat, pooled);
    k_mlp<<<(GG * 400 + B - 1) / B, B, 0, stream>>>(pooled, W3, b3, p400, 200, 400, 0);
    k_mlp<<<(GG * 200 + B - 1) / B, B, 0, stream>>>(p400, F1, bf1, y1, 400, 200, 1);
    k_mlp<<<(GG * 100 + B - 1) / B, B, 0, stream>>>(y1, F2, bf2, y2, 200, 100, 1);
    k_mlp<<<(GG * 100 + B - 1) / B, B, 0, stream>>>(y2, F3, bf3, (float*)d_out, 100, 100, 0);
}

// Round 3
// 1373.288 us; speedup vs baseline: 1.4296x; 1.1816x over previous
//
#include <hip/hip_runtime.h>
#include <cstdint>
#include <climits>
#include <math.h>

#define NN 50000
#define EE 1600000
#define ET (EE + NN)   // real edges + one self-loop per node
#define GG 512
#define NEG_SLOPE 0.2f
#define NB 196          // ceil(NN/256) scan blocks

typedef _Float16 half2v __attribute__((ext_vector_type(2)));

__device__ __forceinline__ uint32_t packh2(float a, float b) {
    union { half2v h; uint32_t u; } c;
    c.h = half2v{(_Float16)a, (_Float16)b};
    return c.u;
}
__device__ __forceinline__ float2 uph(uint32_t u) {
    union { uint32_t u; half2v h; } c;
    c.u = u;
    return make_float2((float)c.h.x, (float)c.h.y);
}
__device__ __forceinline__ float fdot2u(uint32_t a, uint32_t b, float c) {
    union { uint32_t u; half2v h; } ua, ub;
    ua.u = a; ub.u = b;
    return __builtin_amdgcn_fdot2(ua.h, ub.h, c, false);
}
__device__ __forceinline__ float rlanef(float v, int l) {
    return __int_as_float(__builtin_amdgcn_readlane(__float_as_int(v), l));
}

// ---------- degree histogram ----------
__global__ void k_hist(const int* __restrict__ dst, int* __restrict__ hist) {
    int e = blockIdx.x * blockDim.x + threadIdx.x;
    if (e < EE) atomicAdd(&hist[dst[e]], 1);
}

// ---------- CSR build ----------
__global__ void k_scan_a(const int* __restrict__ hist, int* __restrict__ bsum) {
    __shared__ int tmp[256];
    int i = blockIdx.x * 256 + threadIdx.x;
    tmp[threadIdx.x] = (i < NN) ? hist[i] : 0;
    __syncthreads();
    for (int d = 128; d; d >>= 1) {
        if (threadIdx.x < d) tmp[threadIdx.x] += tmp[threadIdx.x + d];
        __syncthreads();
    }
    if (threadIdx.x == 0) bsum[blockIdx.x] = tmp[0];
}

// parallel single-block scan over NB block sums
__global__ void k_scan_b(int* __restrict__ bsum, int* __restrict__ rowptr) {
    __shared__ int tmp[256];
    int t = threadIdx.x;
    int v = (t < NB) ? bsum[t] : 0;
    tmp[t] = v;
    __syncthreads();
    for (int d = 1; d < 256; d <<= 1) {
        int u = (t >= d) ? tmp[t - d] : 0;
        __syncthreads();
        tmp[t] += u;
        __syncthreads();
    }
    if (t < NB) bsum[t] = tmp[t] - v;        // exclusive
    if (t == 255) rowptr[NN] = tmp[255];     // total == EE
}

// rowptr + cursor init fused
__global__ void k_scan_c(const int* __restrict__ hist, const int* __restrict__ bsum,
                         int* __restrict__ rowptr, int* __restrict__ cursor) {
    __shared__ int tmp[256];
    int i = blockIdx.x * 256 + threadIdx.x;
    int v = (i < NN) ? hist[i] : 0;
    tmp[threadIdx.x] = v;
    __syncthreads();
    for (int d = 1; d < 256; d <<= 1) {
        int t = (threadIdx.x >= d) ? tmp[threadIdx.x - d] : 0;
        __syncthreads();
        tmp[threadIdx.x] += t;
        __syncthreads();
    }
    if (i < NN) {
        int rp = tmp[threadIdx.x] - v + bsum[blockIdx.x];
        rowptr[i] = rp;
        cursor[i] = rp;
    }
}

// ---------- scatter + csr_src/csr_dst + fp16 AoS ea pack, one pass ----------
__global__ void k_scatter(const int* __restrict__ srcv, const int* __restrict__ dstv,
                          const float* __restrict__ ea, int* __restrict__ cursor,
                          int* __restrict__ csr_src, int* __restrict__ csr_dst,
                          uint32_t* __restrict__ eaa) {
    int e = blockIdx.x * blockDim.x + threadIdx.x;
    if (e >= EE) return;
    int d = dstv[e];
    int p = atomicAdd(&cursor[d], 1);
    csr_src[p] = srcv[e];
    csr_dst[p] = d;
    const float* r = ea + (size_t)e * 18;
    uint32_t o[12];
#pragma unroll
    for (int kk = 0; kk < 9; kk++) {
        float2 q = *(const float2*)(r + 2 * kk);
        o[kk] = packh2(q.x, q.y);
    }
    o[9] = o[10] = o[11] = 0;
    uint4* dst = (uint4*)(eaa + (size_t)p * 12);
    dst[0] = *(uint4*)&o[0];
    dst[1] = *(uint4*)&o[4];
    dst[2] = *(uint4*)&o[8];
}

// ---------- self-loop edge attr = mean of incoming ea; append virtual edges ----------
__global__ void __launch_bounds__(256)
k_loop2(const int* __restrict__ rowptr, uint32_t* __restrict__ eaa,
        int* __restrict__ csr_src, int* __restrict__ csr_dst) {
    const int lane = threadIdx.x & 63;
    int wid = blockIdx.x * (blockDim.x >> 6) + (threadIdx.x >> 6);
    int nw = gridDim.x * (blockDim.x >> 6);

    for (int i = wid; i < NN; i += nw) {
        int beg = __builtin_amdgcn_readfirstlane(rowptr[i]);
        int end = __builtin_amdgcn_readfirstlane(rowptr[i + 1]);
        float s[18];
#pragma unroll
        for (int j = 0; j < 18; j++) s[j] = 0.f;
        for (int cs = beg; cs < end; cs += 64) {
            int cnt = end - cs; if (cnt > 64) cnt = 64;
            if (lane < cnt) {
                const uint32_t* pe = eaa + (size_t)(cs + lane) * 12;
                uint4 a = *(const uint4*)pe;
                uint4 b = *(const uint4*)(pe + 4);
                uint32_t c = pe[8];
                uint32_t w[9] = {a.x, a.y, a.z, a.w, b.x, b.y, b.z, b.w, c};
#pragma unroll
                for (int kk = 0; kk < 9; kk++) {
                    float2 q = uph(w[kk]);
                    s[2 * kk] += q.x; s[2 * kk + 1] += q.y;
                }
            }
        }
#pragma unroll
        for (int j = 0; j < 18; j++) {
#pragma unroll
            for (int off = 32; off; off >>= 1) s[j] += __shfl_xor(s[j], off, 64);
        }
        if (lane == 0) {
            int deg = end - beg;
            float rd = (deg > 0) ? 1.0f / (float)deg : 0.0f;
            uint32_t o[12];
#pragma unroll
            for (int kk = 0; kk < 9; kk++) o[kk] = packh2(s[2 * kk] * rd, s[2 * kk + 1] * rd);
            o[9] = o[10] = o[11] = 0;
            uint4* dst = (uint4*)(eaa + (size_t)(EE + i) * 12);
            dst[0] = *(uint4*)&o[0];
            dst[1] = *(uint4*)&o[4];
            dst[2] = *(uint4*)&o[8];
            csr_src[EE + i] = i; csr_dst[EE + i] = i;
        }
    }
}

// ---------- pack WeT: group g = 4 features; per feature: 9 fp16-pair dwords + att ----------
__global__ void k_pack_wet(const float* __restrict__ We, const float* __restrict__ att,
                           uint32_t* __restrict__ WeT, int C) {
    int t = blockIdx.x * blockDim.x + threadIdx.x;
    if (t >= C * 10) return;
    int c = t / 10, kk = t - c * 10;
    int g = c >> 2, j = c & 3;
    uint32_t v;
    if (kk < 9) v = packh2(We[(2 * kk) * C + c], We[(2 * kk + 1) * C + c]);
    else v = __float_as_uint(att[c]);
    WeT[g * 40 + j * 10 + kk] = v;
}

// ---------- combine Wl|Wr into padded Wc [K x NP], biases into bc [NP] ----------
__global__ void k_combine_w(const float* __restrict__ Wl, const float* __restrict__ bl,
                            const float* __restrict__ Wr, const float* __restrict__ br,
                            float* __restrict__ Wc, float* __restrict__ bc,
                            int K, int C, int NP) {
    int t = blockIdx.x * blockDim.x + threadIdx.x;
    if (t < K * NP) {
        int k = t / NP, n = t - k * NP;
        float v = 0.0f;
        if (n < C) v = Wl[k * C + n];
        else if (n < 2 * C) v = Wr[k * C + n - C];
        Wc[t] = v;
    }
    if (t < NP) {
        float v = 0.0f;
        if (t < C) v = bl[t];
        else if (t < 2 * C) v = br[t - C];
        bc[t] = v;
    }
}

// ---------- tiled dual GEMM -> xl16/xr16 (packed fp16 only, padded pitch RL) ----------
template <int KK, int NP, int C, int RL>
__global__ void __launch_bounds__(256)
k_gemm_dual(const float* __restrict__ A, const float* __restrict__ Wc,
            const float* __restrict__ bc,
            uint32_t* __restrict__ xl16, uint32_t* __restrict__ xr16) {
    constexpr int BM = 64, BN = 64, BK = 16;
    __shared__ float As[BK][BM];
    __shared__ float Ws[BK][BN];
    const int tidx = threadIdx.x;
    const int tx = tidx & 15;
    const int ty = tidx >> 4;
    const int m0 = blockIdx.x * BM;
    const int n0 = blockIdx.y * BN;

    float acc[4][4];
#pragma unroll
    for (int i2 = 0; i2 < 4; i2++)
#pragma unroll
        for (int j2 = 0; j2 < 4; j2++) acc[i2][j2] = 0.0f;

    for (int k0 = 0; k0 < KK; k0 += BK) {
        {
            int m = tidx >> 2;
            int kq = (tidx & 3) * 4;
            float4 v = make_float4(0.f, 0.f, 0.f, 0.f);
            if (m0 + m < NN && k0 + kq < KK)
                v = *(const float4*)(A + (size_t)(m0 + m) * KK + k0 + kq);
            As[kq + 0][m] = v.x; As[kq + 1][m] = v.y;
            As[kq + 2][m] = v.z; As[kq + 3][m] = v.w;
        }
        {
            int k = tidx >> 4;
            int nq = (tidx & 15) * 4;
            float4 v = make_float4(0.f, 0.f, 0.f, 0.f);
            if (k0 + k < KK)
                v = *(const float4*)(Wc + (size_t)(k0 + k) * NP + n0 + nq);
            *(float4*)&Ws[k][nq] = v;
        }
        __syncthreads();
#pragma unroll
        for (int k = 0; k < BK; k++) {
            float a[4], b[4];
            *(float4*)a = *(const float4*)&As[k][ty * 4];
            *(float4*)b = *(const float4*)&Ws[k][tx * 4];
#pragma unroll
            for (int i2 = 0; i2 < 4; i2++)
#pragma unroll
                for (int j2 = 0; j2 < 4; j2++) acc[i2][j2] += a[i2] * b[j2];
        }
        __syncthreads();
    }

    const int n = n0 + tx * 4;
    float4 bcv = *(const float4*)(bc + n);
#pragma unroll
    for (int i2 = 0; i2 < 4; i2++) {
        int m = m0 + ty * 4 + i2;
        if (m >= NN) continue;
        float4 o = make_float4(acc[i2][0] + bcv.x, acc[i2][1] + bcv.y,
                               acc[i2][2] + bcv.z, acc[i2][3] + bcv.w);
        uint2 p;
        p.x = packh2(o.x, o.y);
        p.y = packh2(o.z, o.w);
        if (n < C)          *(uint2*)(xl16 + (size_t)m * RL + n / 2) = p;
        else if (n < 2 * C) *(uint2*)(xr16 + (size_t)m * RL + (n - C) / 2) = p;
    }
}

// ---------- edge-parallel scores: full fp16 rows preloaded, pinned by sched_barrier ----
template <int C>
__global__ void __launch_bounds__(256, 2)
k_score(const int* __restrict__ csr_src, const int* __restrict__ csr_dst,
        const uint32_t* __restrict__ eaa, const uint32_t* __restrict__ WeT,
        const uint32_t* __restrict__ xl16, const uint32_t* __restrict__ xr16,
        float* __restrict__ scores) {
    constexpr int RL = ((C / 2) + 3) & ~3;   // padded dwords per row
    int pos = blockIdx.x * blockDim.x + threadIdx.x;
    if (pos >= ET) return;
    int s = csr_src[pos];
    int d = csr_dst[pos];

    // issue ALL loads (row src, row dst, edge attr) before any compute
    uint32_t lw[RL], rw[RL];
    const uint4* pl = (const uint4*)(xl16 + (size_t)s * RL);
    const uint4* pr = (const uint4*)(xr16 + (size_t)d * RL);
#pragma unroll
    for (int i = 0; i < RL / 4; i++) *(uint4*)&lw[4 * i] = pl[i];
#pragma unroll
    for (int i = 0; i < RL / 4; i++) *(uint4*)&rw[4 * i] = pr[i];
    const uint32_t* pe = eaa + (size_t)pos * 12;
    uint4 e0 = *(const uint4*)pe;
    uint4 e1 = *(const uint4*)(pe + 4);
    uint32_t e8 = pe[8];
    __builtin_amdgcn_sched_barrier(0);   // pin: loads issued before compute

    uint32_t ean[9] = {e0.x, e0.y, e0.z, e0.w, e1.x, e1.y, e1.z, e1.w, e8};

    float score = 0.0f;
#pragma unroll
    for (int g = 0; g < C / 4; g++) {
        const uint32_t* wg = WeT + g * 40;   // wave-uniform -> scalar loads
        union { uint32_t u; half2v h; } a0, b0, a1v, b1v, u0, u1;
        a0.u = lw[2 * g];     b0.u = rw[2 * g];
        a1v.u = lw[2 * g + 1]; b1v.u = rw[2 * g + 1];
        u0.h = a0.h + b0.h;   // v_pk_add_f16: xl + xr
        u1.h = a1v.h + b1v.h;
        float lv[4] = {(float)u0.h.x, (float)u0.h.y, (float)u1.h.x, (float)u1.h.y};
#pragma unroll
        for (int j = 0; j < 4; j++) {
            float w = 0.0f;
#pragma unroll
            for (int kk = 0; kk < 9; kk++) w = fdot2u(ean[kk], wg[j * 10 + kk], w);
            float u = lv[j] + w;
            float h = fmaxf(u, NEG_SLOPE * u);
            score = fmaf(__uint_as_float(wg[j * 10 + 9]), h, score);
        }
    }
    scores[pos] = score;
}

// ---------- per-node exact softmax + aggregation from fp16 rows (wave per node) -----
template <int C, int VEC, int RELU>
__global__ void __launch_bounds__(256)
k_fin(const int* __restrict__ rowptr, const int* __restrict__ csr_src,
      const float* __restrict__ scores, const uint32_t* __restrict__ xl16,
      const float* __restrict__ bias, float* __restrict__ out) {
    constexpr int DW = VEC / 2;              // dwords per lane per row
    constexpr int RL = ((C / 2) + 3) & ~3;   // row pitch in dwords
    constexpr int NL = C / VEC;
    const int lane = threadIdx.x & 63;
    int wid = blockIdx.x * (blockDim.x >> 6) + (threadIdx.x >> 6);
    int nw = gridDim.x * (blockDim.x >> 6);
    const bool act = lane < NL;

    float bv[VEC];
    if (act) {
#pragma unroll
        for (int j = 0; j < VEC; j++) bv[j] = bias[lane * VEC + j];
    } else {
#pragma unroll
        for (int j = 0; j < VEC; j++) bv[j] = 0.f;
    }

    auto ldrow = [&](uint32_t (&buf)[DW], int node) {
        if (act) {
            if constexpr (DW == 2) {
                uint2 v = *(const uint2*)(xl16 + (size_t)node * RL + lane * 2);
                buf[0] = v.x; buf[1] = v.y;
            } else {
                buf[0] = xl16[(size_t)node * RL + lane];
            }
        } else {
#pragma unroll
            for (int q = 0; q < DW; q++) buf[q] = 0;
        }
    };

    for (int i = wid; i < NN; i += nw) {
        int beg = __builtin_amdgcn_readfirstlane(rowptr[i]);
        int end = __builtin_amdgcn_readfirstlane(rowptr[i + 1]);
        float s_self = scores[EE + i];

        // pass 1: exact max
        float m = s_self;
        for (int cs = beg; cs < end; cs += 64) {
            int cnt = end - cs; if (cnt > 64) cnt = 64;
            float sc = (lane < cnt) ? scores[cs + lane] : -INFINITY;
#pragma unroll
            for (int off = 32; off; off >>= 1) sc = fmaxf(sc, __shfl_xor(sc, off, 64));
            m = fmaxf(m, sc);
        }

        // self-loop contribution
        float acc[VEC];
        float pes = __expf(s_self - m);
        float z = pes;
        {
            uint32_t w[DW];
            ldrow(w, i);
#pragma unroll
            for (int q = 0; q < DW; q++) {
                float2 f = uph(w[q]);
                acc[2 * q] = pes * f.x;
                acc[2 * q + 1] = pes * f.y;
            }
        }

        // pass 2: exp + denom + aggregation (8-deep prefetch, fp16 rows)
        for (int cs = beg; cs < end; cs += 64) {
            int cnt = end - cs; if (cnt > 64) cnt = 64;
            float sc = (lane < cnt) ? scores[cs + lane] : -INFINITY;
            int srcl = (lane < cnt) ? csr_src[cs + lane] : 0;
            float pe = __expf(sc - m);
            float zc = pe;
#pragma unroll
            for (int off = 32; off; off >>= 1) zc += __shfl_xor(zc, off, 64);
            z += zc;

            uint32_t A[4][DW], Bv[4][DW];
            auto LD4 = [&](uint32_t (&buf)[4][DW], int t0) {
#pragma unroll
                for (int q = 0; q < 4; q++) {
                    int t = t0 + q;
                    if (t < cnt) {
                        int sx = __builtin_amdgcn_readlane(srcl, t);
                        ldrow(buf[q], sx);
                    }
                }
            };
            auto USE4 = [&](uint32_t (&buf)[4][DW], int t0) {
#pragma unroll
                for (int q = 0; q < 4; q++) {
                    int t = t0 + q;
                    if (t < cnt) {
                        float a = rlanef(pe, t);
#pragma unroll
                        for (int qq = 0; qq < DW; qq++) {
                            float2 f = uph(buf[q][qq]);
                            acc[2 * qq] = fmaf(a, f.x, acc[2 * qq]);
                            acc[2 * qq + 1] = fmaf(a, f.y, acc[2 * qq + 1]);
                        }
                    }
                }
            };
            LD4(A, 0);
            for (int t0 = 0; t0 < cnt; t0 += 8) {
                if (t0 + 4 < cnt) LD4(Bv, t0 + 4);
                __builtin_amdgcn_sched_barrier(0);
                USE4(A, t0);
                if (t0 + 8 < cnt) LD4(A, t0 + 8);
                __builtin_amdgcn_sched_barrier(0);
                USE4(Bv, t0 + 4);
            }
        }

        float rz = 1.0f / z;
        if (act) {
            float o[VEC];
#pragma unroll
            for (int j = 0; j < VEC; j++) {
                o[j] = acc[j] * rz + bv[j];
                if (RELU) o[j] = fmaxf(o[j], 0.0f);
            }
            if constexpr (VEC == 4) {
                *(float4*)(out + (size_t)i * C + lane * 4) = make_float4(o[0], o[1], o[2], o[3]);
            } else {
                *(float2*)(out + (size_t)i * C + lane * 2) = make_float2(o[0], o[1]);
            }
        }
    }
}

// ---------- mean pooling per graph (batch_ids sorted); relu folded in ----------
__global__ void k_pool(const float* __restrict__ h, const int* __restrict__ batch,
                       float* __restrict__ pooled) {
    int g = blockIdx.x;
    int lo = 0, hi = NN;
    while (lo < hi) { int mid = (lo + hi) >> 1; if (batch[mid] < g) lo = mid + 1; else hi = mid; }
    int start = lo;
    lo = start; hi = NN;
    while (lo < hi) { int mid = (lo + hi) >> 1; if (batch[mid] < g + 1) lo = mid + 1; else hi = mid; }
    int end = lo;
    float cnt = (float)(end - start);
    int c = threadIdx.x;
    if (c < 200) {
        float acc = 0.0f;
        for (int i = start; i < end; i++) acc += fmaxf(h[(size_t)i * 200 + c], 0.0f);
        pooled[g * 200 + c] = acc / fmaxf(cnt, 1.0f);
    }
}

// ---------- small dense layers on [G, *] ----------
__global__ void k_mlp(const float* __restrict__ X, const float* __restrict__ W,
                      const float* __restrict__ b, float* __restrict__ Y,
                      int Cin, int Cout, int do_relu) {
    int t = blockIdx.x * blockDim.x + threadIdx.x;
    if (t >= GG * Cout) return;
    int g = t / Cout, j = t - g * Cout;
    const float* xrow = X + (size_t)g * Cin;
    float acc = b[j];
    for (int k = 0; k < Cin; k++) acc += xrow[k] * W[k * Cout + j];
    if (do_relu) acc = fmaxf(acc, 0.0f);
    Y[t] = acc;
}

extern "C" void kernel_launch(void* const* d_in, const int* in_sizes, int n_in,
                              void* d_out, int out_size, void* d_ws, size_t ws_size,
                              hipStream_t stream) {
    const float* x   = (const float*)d_in[0];
    const int*   ei  = (const int*)d_in[1];
    const float* ea  = (const float*)d_in[2];
    const int*   bat = (const int*)d_in[3];
    const float* W1l = (const float*)d_in[4];  const float* b1l = (const float*)d_in[5];
    const float* W1r = (const float*)d_in[6];  const float* b1r = (const float*)d_in[7];
    const float* W1e = (const float*)d_in[8];
    const float* a1  = (const float*)d_in[9];  const float* c1  = (const float*)d_in[10];
    const float* W2l = (const float*)d_in[11]; const float* b2l = (const float*)d_in[12];
    const float* W2r = (const float*)d_in[13]; const float* b2r = (const float*)d_in[14];
    const float* W2e = (const float*)d_in[15];
    const float* a2  = (const float*)d_in[16]; const float* c2  = (const float*)d_in[17];
    const float* W3  = (const float*)d_in[18]; const float* b3  = (const float*)d_in[19];
    const float* F1  = (const float*)d_in[20]; const float* bf1 = (const float*)d_in[21];
    const float* F2  = (const float*)d_in[22]; const float* bf2 = (const float*)d_in[23];
    const float* F3  = (const float*)d_in[24]; const float* bf3 = (const float*)d_in[25];

    const int* srcv = ei;        // edge_index[0]
    const int* dstv = ei + EE;   // edge_index[1]

    float* W = (float*)d_ws;
    size_t off = 0;
    int*      hist    = (int*)(W + off); off += NN;
    float*    h1      = W + off; off += (size_t)NN * 100;
    float*    h2      = W + off; off += (size_t)NN * 200;
    int*      rowptr  = (int*)(W + off); off += NN + 4;
    int*      cursor  = (int*)(W + off); off += NN;
    int*      bsum    = (int*)(W + off); off += 256;
    float*    scores  = W + off; off += ET;
    int*      csr_src = (int*)(W + off); off += ET;
    int*      csr_dst = (int*)(W + off); off += ET;
    uint32_t* eaa     = (uint32_t*)(W + off); off += (size_t)ET * 12;
    uint32_t* xl16    = (uint32_t*)(W + off); off += (size_t)NN * 100;
    uint32_t* xr16    = (uint32_t*)(W + off); off += (size_t)NN * 100;
    uint32_t* WeT1    = (uint32_t*)(W + off); off += 25 * 40;
    uint32_t* WeT2    = (uint32_t*)(W + off); off += 50 * 40;
    float*    Wc1     = W + off; off += 16 * 256;
    float*    bc1     = W + off; off += 256;
    float*    Wc2     = W + off; off += 100 * 448;
    float*    bc2     = W + off; off += 448;
    float*    pooled  = W + off; off += (size_t)GG * 200;
    float*    p400    = W + off; off += (size_t)GG * 400;
    float*    y1      = W + off; off += (size_t)GG * 200;
    float*    y2      = W + off; off += (size_t)GG * 100;
    (void)ws_size; (void)n_in; (void)in_sizes; (void)out_size;

    const int B = 256;
    const int NODEB = 12500;   // 4 waves/block -> 50000 waves, 1 node each

    // ---- degree histogram + CSR by dst; scatter also packs ea + src/dst ----
    hipMemsetAsync(hist, 0, (size_t)NN * sizeof(int), stream);
    k_hist<<<(EE + B - 1) / B, B, 0, stream>>>(dstv, hist);
    k_scan_a<<<NB, 256, 0, stream>>>(hist, bsum);
    k_scan_b<<<1, 256, 0, stream>>>(bsum, rowptr);
    k_scan_c<<<NB, 256, 0, stream>>>(hist, bsum, rowptr, cursor);
    k_scatter<<<(EE + B - 1) / B, B, 0, stream>>>(srcv, dstv, ea, cursor, csr_src, csr_dst, eaa);
    k_loop2<<<NODEB, B, 0, stream>>>(rowptr, eaa, csr_src, csr_dst);

    // ---- weight prep ----
    k_pack_wet<<<(100 * 10 + B - 1) / B, B, 0, stream>>>(W1e, a1, WeT1, 100);
    k_pack_wet<<<(200 * 10 + B - 1) / B, B, 0, stream>>>(W2e, a2, WeT2, 200);
    k_combine_w<<<(16 * 256 + B - 1) / B, B, 0, stream>>>(W1l, b1l, W1r, b1r, Wc1, bc1, 16, 100, 256);
    k_combine_w<<<(100 * 448 + B - 1) / B, B, 0, stream>>>(W2l, b2l, W2r, b2r, Wc2, bc2, 100, 200, 448);

    // ---- GAT layer 1: 16 -> 100 (RL = 52) ----
    {
        dim3 grid((NN + 63) / 64, 256 / 64);
        k_gemm_dual<16, 256, 100, 52><<<grid, 256, 0, stream>>>(x, Wc1, bc1, xl16, xr16);
    }
    k_score<100><<<(ET + B - 1) / B, B, 0, stream>>>(csr_src, csr_dst, eaa, WeT1, xl16, xr16, scores);
    k_fin<100, 2, 1><<<NODEB, B, 0, stream>>>(rowptr, csr_src, scores, xl16, c1, h1);

    // ---- GAT layer 2: 100 -> 200 (RL = 100) ----
    {
        dim3 grid((NN + 63) / 64, 448 / 64);
        k_gemm_dual<100, 448, 200, 100><<<grid, 256, 0, stream>>>(h1, Wc2, bc2, xl16, xr16);
    }
    k_score<200><<<(ET + B - 1) / B, B, 0, stream>>>(csr_src, csr_dst, eaa, WeT2, xl16, xr16, scores);
    k_fin<200, 4, 0><<<NODEB, B, 0, stream>>>(rowptr, csr_src, scores, xl16, c2, h2);

    // ---- pool (mean over graph, relu fused) then W3 + FFN ----
    k_pool<<<GG, 256, 0, stream>>>(h2, bat, pooled);
    k_mlp<<<(GG * 400 + B - 1) / B, B, 0, stream>>>(pooled, W3, b3, p400, 200, 400, 0);
    k_mlp<<<(GG * 200 + B - 1) / B, B, 0, stream>>>(p400, F1, bf1, y1, 400, 200, 1);
    k_mlp<<<(GG * 100 + B - 1) / B, B, 0, stream>>>(y1, F2, bf2, y2, 200, 100, 1);
    k_mlp<<<(GG * 100 + B - 1) / B, B, 0, stream>>>(y2, F3, bf3, (float*)d_out, 100, 100, 0);
}